// Round 6
// baseline (273.903 us; speedup 1.0000x reference)
//
#include <hip/hip_runtime.h>

// B=4, S=2048, D=1024, H=16, DK=64. RoPE (interleaved pairs) + causal MHA.
// R3: attention rewrite — no-max softmax, K=16 PV MFMA, merged q-tile pairs.
// R4: attn3 dbuf K/V prefetch + XCD-grouping block remap.
// R5: gemm 2-phase pipeline (dbuf LDS, prefetch-before-compute).
// R6: attn3 two q-tile pairs per block; fused cast_all.
// R7: gemm natural block order; RoPE fused into QKV epilogue (rope_tab).
// R8: attn3 32-col waves (neutral: proved attn is stall-bound, not LDS/VALU).
// R9 (this round): gemm128 -> gemm_p, counted-vmcnt pipeline (T3+T4):
// 128x256 tile, 512 thr (8 waves 2Mx4N), K in 32 k-halves of 32 staged into
// a 4-slot LDS ring (96KB). Per phase: stage(kh+2) [3 glds] -> vmcnt(6)
// (NEVER 0 in-loop: 2 slots stay in flight) -> barrier -> 8 ds_read_b128 ->
// 16 MFMA. WAR: slot written at kh last read kh-2, fenced by kh-1 barrier.
// RAW: slot read at kh staged kh-2, proven done by vmcnt(6)+barrier.
// Grids: QKV (64,12)=768 = 3 exact CU rounds; out-proj (64,4)=256 = 1 round.

typedef unsigned short u16;
typedef unsigned int u32;
typedef __attribute__((ext_vector_type(8))) short bf16x8;
typedef __attribute__((ext_vector_type(4))) short bf16x4;
typedef __attribute__((ext_vector_type(4))) float f32x4;
typedef __attribute__((ext_vector_type(4))) unsigned short u16x4;

#define S_LEN 2048
#define DMODEL 1024
#define NHEAD 16
#define DKH 64
#define BATCH 4
#define NT 32  // S_LEN/64 key tiles
#define NX4 (BATCH * S_LEN * DMODEL / 4)  // 2097152
#define NW4 (DMODEL * DMODEL / 4)         // 262144 = 2^18

static __device__ __forceinline__ u16 f2bf(float f) {
  union { float f; u32 u; } v; v.f = f;
  u32 r = v.u + 0x7fffu + ((v.u >> 16) & 1u);  // RNE
  return (u16)(r >> 16);
}
#if __has_builtin(__builtin_amdgcn_cvt_pk_bf16_f32)
typedef __attribute__((ext_vector_type(2))) __bf16 bf2_t;
static __device__ __forceinline__ u32 pack2bf(float a, float b) {
  union { bf2_t h; u32 u; } cv;
  cv.h = __builtin_amdgcn_cvt_pk_bf16_f32(a, b);
  return cv.u;
}
#else
static __device__ __forceinline__ u32 pack2bf(float a, float b) {
  return (u32)f2bf(a) | ((u32)f2bf(b) << 16);
}
#endif
static __device__ __forceinline__ float fexp2(float x) {
#if __has_builtin(__builtin_amdgcn_exp2f)
  return __builtin_amdgcn_exp2f(x);
#else
  return exp2f(x);
#endif
}
static __device__ __forceinline__ f32x4 mfma16(bf16x8 a, bf16x8 b, f32x4 c) {
  return __builtin_amdgcn_mfma_f32_16x16x32_bf16(a, b, c, 0, 0, 0);
}
#if __has_builtin(__builtin_amdgcn_mfma_f32_16x16x16bf16_1k)
#define HAVE_MFMA_K16 1
static __device__ __forceinline__ f32x4 mfma16k16(bf16x4 a, bf16x4 b, f32x4 c) {
  return __builtin_amdgcn_mfma_f32_16x16x16bf16_1k(a, b, c, 0, 0, 0);
}
#else
#define HAVE_MFMA_K16 0
#endif
// Async global->LDS, 16B per lane. LDS dest = wave-uniform base + lane*16.
static __device__ __forceinline__ void glds16(const void* g, void* l) {
  __builtin_amdgcn_global_load_lds((const __attribute__((address_space(1))) u32*)g,
                                   (__attribute__((address_space(3))) u32*)l, 16, 0, 0);
}

// One fused cast pass: x (8M f32) + Wq,Wk,Wv -> Wcat + Wo -> Wob.
__global__ __launch_bounds__(256) void cast_all(const float* __restrict__ x,
                                                const float* __restrict__ Wq,
                                                const float* __restrict__ Wk,
                                                const float* __restrict__ Wv,
                                                const float* __restrict__ Wo,
                                                u16* __restrict__ xb,
                                                u16* __restrict__ Wcat,
                                                u16* __restrict__ Wob) {
  int i = blockIdx.x * 256 + threadIdx.x;
  const float* s;
  u16* d;
  if (i < NX4) {
    s = x + (size_t)i * 4;
    d = xb + (size_t)i * 4;
  } else {
    int j = i - NX4;
    int r = j >> 18;
    int off = j & (NW4 - 1);
    const float* W = r == 0 ? Wq : r == 1 ? Wk : r == 2 ? Wv : Wo;
    s = W + (size_t)off * 4;
    d = (r < 3 ? Wcat + (size_t)r * DMODEL * DMODEL : Wob) + (size_t)off * 4;
  }
  u16x4 o;
  o.x = f2bf(s[0]); o.y = f2bf(s[1]); o.z = f2bf(s[2]); o.w = f2bf(s[3]);
  *(u16x4*)d = o;
}

// cos/sin table for RoPE: tab[s*32+p] = {cos, sin}(pos[s] * 10000^(-2p/64)).
__global__ __launch_bounds__(256) void rope_tab(const int* __restrict__ pos,
                                                float2* __restrict__ tab) {
  int i = blockIdx.x * 256 + threadIdx.x;  // over 2048*32
  int s = i >> 5, p = i & 31;
  float ph = (float)pos[s] * powf(10000.0f, -(float)(2 * p) / 64.0f);
  float sn, cs;
  sincosf(ph, &sn, &cs);
  tab[i] = make_float2(cs, sn);
}

// Counted-vmcnt pipelined GEMM. C[m,n] = sum_k A[m,k]*W[n,k].
// Tile 128x256, 512 threads = 8 waves (2M x 4N), per-wave 64x64 output.
// K staged as 32 k-halves (32 cols each) in a 4-slot LDS ring:
//   phase kh: stage slot (kh+2)&3 [1 A-glds + 2 B-glds per thread],
//             vmcnt(6) [keeps newest 2 slots in flight], barrier,
//             8 ds_read_b128 from slot kh&3, 16 MFMA.
// Swizzle: k-chunk (8 u16 = 16B) stored at chunk^(row&3); staging source
// pre-swizzled so glds dest stays linear; reads use quad^(c&3). 2-way bank
// aliasing on b128 reads = free (m136).
// mode 0: QKV epilogue with fused RoPE; mode 2: fp32 store to of.
__global__ __launch_bounds__(512, 2) void gemm_p(const u16* __restrict__ A,
                                                 const u16* __restrict__ W,
                                                 u16* __restrict__ oq,
                                                 u16* __restrict__ ok,
                                                 u16* __restrict__ ov,
                                                 float* __restrict__ of,
                                                 const float2* __restrict__ tab,
                                                 int mode) {
  __shared__ __attribute__((aligned(16))) u16 As[4][128 * 32];  // 32 KB
  __shared__ __attribute__((aligned(16))) u16 Bs[4][256 * 32];  // 64 KB
  const int m0 = blockIdx.x * 128, n0 = blockIdx.y * 256;
  const int tid = threadIdx.x, lane = tid & 63, wave = tid >> 6;
  const int quad = lane >> 4, c = lane & 15;
  const int wm = (wave & 1) * 64, wn = (wave >> 1) * 64;
  const int sx = 8 * (quad ^ (c & 3));               // read swizzle offset
  const int srow = lane >> 2;                        // staging row in group
  const int schunk = 8 * ((lane & 3) ^ (srow & 3));  // staging src col

  // stage k-half kh of A (1 glds) / B (2 glds) into ring slot
  auto stageA = [&](int slot, int kh) {
    int r = wave * 16 + srow;  // 8 groups x 16 rows = 128
    glds16(&A[(size_t)(m0 + r) * DMODEL + kh * 32 + schunk], &As[slot][wave * 512]);
  };
  auto stageB = [&](int slot, int kh) {
#pragma unroll
    for (int i = 0; i < 2; ++i) {
      int grp = i * 8 + wave;  // 16 groups x 16 rows = 256
      int r = grp * 16 + srow;
      glds16(&W[(size_t)(n0 + r) * DMODEL + kh * 32 + schunk], &Bs[slot][grp * 512]);
    }
  };

  f32x4 acc[4][4] = {};
  // prologue: slots 0,1 (k-halves 0,1) in flight
  stageA(0, 0); stageB(0, 0);
  stageA(1, 1); stageB(1, 1);
#pragma unroll 1
  for (int kh = 0; kh < 32; ++kh) {
    const int slot = kh & 3;
    const int st = (kh + 2 <= 31) ? kh + 2 : 31;  // clamp: tail restage is
    const int sslot = (kh + 2) & 3;               // garbage into dead slots
    stageA(sslot, st);
    stageB(sslot, st);
    asm volatile("s_waitcnt vmcnt(6)" ::: "memory");  // slot kh done; 2 newer in flight
    __builtin_amdgcn_s_barrier();
    __builtin_amdgcn_sched_barrier(0);
    bf16x8 af[4], bfr[4];
#pragma unroll
    for (int mf = 0; mf < 4; ++mf)
      af[mf] = *(const bf16x8*)&As[slot][(wm + mf * 16 + c) * 32 + sx];
#pragma unroll
    for (int nf = 0; nf < 4; ++nf)
      bfr[nf] = *(const bf16x8*)&Bs[slot][(wn + nf * 16 + c) * 32 + sx];
    __builtin_amdgcn_s_setprio(1);
#pragma unroll
    for (int mf = 0; mf < 4; ++mf)
#pragma unroll
      for (int nf = 0; nf < 4; ++nf)
        acc[mf][nf] = mfma16(af[mf], bfr[nf], acc[mf][nf]);
    __builtin_amdgcn_s_setprio(0);
  }

#pragma unroll
  for (int mf = 0; mf < 4; ++mf) {
    int mrow = m0 + wm + mf * 16 + quad * 4;
#pragma unroll
    for (int nf = 0; nf < 4; ++nf) {
      int n = n0 + wn + nf * 16 + c;
      f32x4 v = acc[mf][nf];
      if (mode == 2) {
#pragma unroll
        for (int r = 0; r < 4; ++r) of[(size_t)(mrow + r) * DMODEL + n] = v[r];
      } else if (n < 2 * DMODEL) {
        // fused RoPE: pair partner (d^1) is in neighbor lane (c parity == n
        // parity: n0/wn/nf*16 all even). Wave-uniform branch region.
        const bool isq = n < DMODEL;
        const int p = (n & 63) >> 1;  // pair index within head
        const bool odd = n & 1;
        u16* dst = isq ? oq : ok;
        const int ncol = n & (DMODEL - 1);
#pragma unroll
        for (int r = 0; r < 4; ++r) {
          float v1 = v[r];
          float v2 = __shfl_xor(v1, 1);
          float x1 = odd ? v2 : v1;
          float x2 = odd ? v1 : v2;
          int s = (mrow + r) & (S_LEN - 1);
          float2 t2 = tab[s * 32 + p];
          float rv = odd ? (x1 * t2.y + x2 * t2.x) : (x1 * t2.x - x2 * t2.y);
          if (isq) rv *= 0.18033688011112042f;  // 0.125 * log2(e)
          dst[(size_t)(mrow + r) * DMODEL + ncol] = f2bf(rv);
        }
      } else {
        int nn = n - 2 * DMODEL;
        int h = nn >> 6, d = nn & 63;
        int b = mrow >> 11, s = mrow & (S_LEN - 1);
        u16x4 p4;
        p4.x = f2bf(v[0]); p4.y = f2bf(v[1]); p4.z = f2bf(v[2]); p4.w = f2bf(v[3]);
        *(u16x4*)&ov[((size_t)(b * NHEAD + h) * DKH + d) * S_LEN + s] = p4;
      }
    }
  }
}

// Flash attention, S^T formulation, no-max softmax. (R8 structure.)
// Grid (8, B*H), 256 threads (4 waves). Block owns TWO merged q-tile pairs:
//   waves 0-1: pair A = (2x, 31-2x); waves 2-3: pair B = (2x+1, 30-2x).
// Each wave owns 32 q-cols (col-half = wave&1) as two 16-col groups. XCD
// remap keeps each (b,h)'s 8 blocks on one XCD. setprio around MFMA.
__global__ __launch_bounds__(256, 2) void attn3(const u16* __restrict__ qb,
                                                const u16* __restrict__ kb,
                                                const u16* __restrict__ vt,
                                                u16* __restrict__ ab) {
  __shared__ __attribute__((aligned(16))) u16 Ks[2][64 * 64];  // [key][d] swizzled
  __shared__ __attribute__((aligned(16))) u16 Vs[2][64 * 64];  // [d][key] swizzled
  const int L = blockIdx.x + 8 * blockIdx.y;
  const int xcd = L & 7, slot = L >> 3;   // slot in [0,64)
  const int bhl = slot >> 3;              // local head in [0,8)
  const int xs = slot & 7;
  const int x = (bhl & 4) ? 7 - xs : xs;  // complementary-x tail balance
  const int bh = xcd * 8 + bhl;
  const int b = bh >> 4, h = bh & 15;
  const int tid = threadIdx.x, lane = tid & 63, wave = tid >> 6;
  const int g = wave >> 1;   // 0: pair A, 1: pair B
  const int wh = wave & 1;   // 32-col half within tile
  const int quad = lane >> 4, c = lane & 15;
  const int ls = lane >> 3, lc = lane & 7;
  const int wq0 = wh * 32;   // base q-col of this wave's 32 cols
  const int qtl = 2 * x + g, qth = 31 - 2 * x - g;
  const int J = 31 - 2 * x;  // loop bound = pair A's qt2
  const float NEG = -3.0e38f;

  // qf[t][cg][dh]: q fragment for tile t, 16-col group cg, d-half dh
  bf16x8 qf[2][2][2];
#pragma unroll
  for (int t = 0; t < 2; ++t)
#pragma unroll
    for (int cg = 0; cg < 2; ++cg) {
      int qrow = (t ? qth : qtl) * 64 + wq0 + cg * 16 + c;
      const u16* qp = qb + (size_t)(b * S_LEN + qrow) * DMODEL + h * DKH;
      qf[t][cg][0] = *(const bf16x8*)&qp[quad * 8];
      qf[t][cg][1] = *(const bf16x8*)&qp[32 + quad * 8];
    }
  float li[2][2] = {};
  f32x4 od[2][2][4] = {};

  // stage tile j into buffer buf: 4 waves x 16 rows each (K and V), no wait
  auto stage = [&](int buf, int j) {
#pragma unroll
    for (int i = 0; i < 2; ++i) {
      int rb = wave * 16 + i * 8;
      int r = rb + ls;
      int col = 8 * (lc ^ (r & 7));
      glds16(&kb[(size_t)(b * S_LEN + j * 64 + r) * DMODEL + h * DKH + col],
             &Ks[buf][rb * 64]);
      glds16(&vt[((size_t)bh * DKH + r) * S_LEN + j * 64 + col],
             &Vs[buf][rb * 64]);
    }
  };

  // one q-tile application (32 cols = 2 col-groups) against buffer cur
  auto apply = [&](int t, int cur, bool diag) {
    f32x4 sc[2][4];
    __builtin_amdgcn_s_setprio(1);
#pragma unroll
    for (int kbi = 0; kbi < 4; ++kbi) {
      int r = kbi * 16 + c;
      bf16x8 k0 = *(const bf16x8*)&Ks[cur][r * 64 + 8 * (quad ^ (r & 7))];
      bf16x8 k1 = *(const bf16x8*)&Ks[cur][r * 64 + 8 * ((4 + quad) ^ (r & 7))];
#pragma unroll
      for (int cg = 0; cg < 2; ++cg) {
        f32x4 a = {};
        a = mfma16(k0, qf[t][cg][0], a);
        a = mfma16(k1, qf[t][cg][1], a);
        sc[cg][kbi] = a;  // already log2-domain (q pre-scaled)
      }
    }
    __builtin_amdgcn_s_setprio(0);
    if (diag) {
#pragma unroll
      for (int cg = 0; cg < 2; ++cg)
#pragma unroll
        for (int kbi = 0; kbi < 4; ++kbi)
#pragma unroll
          for (int r = 0; r < 4; ++r)
            if (kbi * 16 + quad * 4 + r > wq0 + cg * 16 + c) sc[cg][kbi][r] = NEG;
    }
    float rs[2] = {0.f, 0.f};
#pragma unroll
    for (int cg = 0; cg < 2; ++cg)
#pragma unroll
      for (int kbi = 0; kbi < 4; ++kbi)
#pragma unroll
        for (int r = 0; r < 4; ++r) {
          float p = fexp2(sc[cg][kbi][r]);
          sc[cg][kbi][r] = p;
          rs[cg] += p;
        }
#pragma unroll
    for (int cg = 0; cg < 2; ++cg) {
      float v = rs[cg];
      v += __shfl_xor(v, 16);
      v += __shfl_xor(v, 32);
      li[t][cg] += v;
    }
#if HAVE_MFMA_K16
    // pkv[cg][kbi] = keys kbi*16+quad*4+{0..3} for q-col c == 16x16x16 B-frag
    bf16x4 pkv[2][4];
#pragma unroll
    for (int cg = 0; cg < 2; ++cg)
#pragma unroll
      for (int kbi = 0; kbi < 4; ++kbi) {
        union { u32 w[2]; bf16x4 v; } pk;
        pk.w[0] = pack2bf(sc[cg][kbi][0], sc[cg][kbi][1]);
        pk.w[1] = pack2bf(sc[cg][kbi][2], sc[cg][kbi][3]);
        pkv[cg][kbi] = pk.v;
      }
    __builtin_amdgcn_s_setprio(1);
#pragma unroll
    for (int db = 0; db < 4; ++db) {
      int r = db * 16 + c;
#pragma unroll
      for (int kbi = 0; kbi < 4; ++kbi) {
        int g2 = kbi * 2 + (quad >> 1);
        bf16x4 vf = *(const bf16x4*)&Vs[cur][r * 64 + 8 * (g2 ^ (r & 7)) + (quad & 1) * 4];
        od[t][0][db] = mfma16k16(vf, pkv[0][kbi], od[t][0][db]);
        od[t][1][db] = mfma16k16(vf, pkv[1][kbi], od[t][1][db]);
      }
    }
    __builtin_amdgcn_s_setprio(0);
#else
    // fallback: shuffle P^T into K=32 B-frag layout, per col-group
#pragma unroll
    for (int cg = 0; cg < 2; ++cg) {
      u32 pk[4][2];
#pragma unroll
      for (int kbi = 0; kbi < 4; ++kbi) {
        pk[kbi][0] = pack2bf(sc[cg][kbi][0], sc[cg][kbi][1]);
        pk[kbi][1] = pack2bf(sc[cg][kbi][2], sc[cg][kbi][3]);
      }
      const int s0 = ((quad & 1) * 2) * 16 + c;
      const int s1 = s0 + 16;
      const bool hi = quad >= 2;
#pragma unroll
      for (int base = 0; base < 2; ++base) {
        u32 e0 = __shfl(pk[base * 2][0], s0);
        u32 e1 = __shfl(pk[base * 2][1], s0);
        u32 e2 = __shfl(pk[base * 2][0], s1);
        u32 e3 = __shfl(pk[base * 2][1], s1);
        u32 o0 = __shfl(pk[base * 2 + 1][0], s0);
        u32 o1 = __shfl(pk[base * 2 + 1][1], s0);
        u32 o2 = __shfl(pk[base * 2 + 1][0], s1);
        u32 o3 = __shfl(pk[base * 2 + 1][1], s1);
        union { u32 w[4]; bf16x8 v; } pf;
        pf.w[0] = hi ? o0 : e0;
        pf.w[1] = hi ? o1 : e1;
        pf.w[2] = hi ? o2 : e2;
        pf.w[3] = hi ? o3 : e3;
#pragma unroll
        for (int db = 0; db < 4; ++db) {
          int r = db * 16 + c;
          bf16x8 vf = *(const bf16x8*)&Vs[cur][r * 64 + 8 * ((base * 4 + quad) ^ (c & 7))];
          od[t][cg][db] = mfma16(vf, pf.v, od[t][cg][db]);
        }
      }
    }
#endif
  };

  // prologue: stage tile 0 into buffer 0, wait (syncthreads drains vmcnt)
  stage(0, 0);
  __syncthreads();
#pragma unroll 1
  for (int j = 0; j <= J; ++j) {
    int cur = j & 1;
    if (j < J) stage(cur ^ 1, j + 1);  // prefetch next tile, no wait
    if (j <= qtl) apply(0, cur, j == qtl);
    if (j <= qth) apply(1, cur, j == qth);
    __syncthreads();  // vmcnt(0)+lgkmcnt(0)+barrier: next buffer ready
  }

#pragma unroll
  for (int t = 0; t < 2; ++t)
#pragma unroll
    for (int cg = 0; cg < 2; ++cg) {
      float inv = 1.0f / li[t][cg];
      int qrow = (t ? qth : qtl) * 64 + wq0 + cg * 16 + c;
      u16* op = ab + (size_t)(b * S_LEN + qrow) * DMODEL + h * DKH;
#pragma unroll
      for (int db = 0; db < 4; ++db) {
        u16x4 o4;
        o4.x = f2bf(od[t][cg][db][0] * inv);
        o4.y = f2bf(od[t][cg][db][1] * inv);
        o4.z = f2bf(od[t][cg][db][2] * inv);
        o4.w = f2bf(od[t][cg][db][3] * inv);
        *(u16x4*)&op[db * 16 + quad * 4] = o4;
      }
    }
}

extern "C" void kernel_launch(void* const* d_in, const int* in_sizes, int n_in,
                              void* d_out, int out_size, void* d_ws, size_t ws_size,
                              hipStream_t stream) {
  const float* x = (const float*)d_in[0];
  const int* pos = (const int*)d_in[1];
  const float* Wq = (const float*)d_in[2];
  const float* Wk = (const float*)d_in[3];
  const float* Wv = (const float*)d_in[4];
  const float* Wo = (const float*)d_in[5];
  float* out = (float*)d_out;

  char* w = (char*)d_ws;
  size_t o = 0;
  auto take = [&](size_t nbytes) {
    char* p = w + o;
    o += (nbytes + 255) & ~(size_t)255;
    return p;
  };
  const size_t actBytes = (size_t)BATCH * S_LEN * DMODEL * 2;
  const size_t wBytes = (size_t)DMODEL * DMODEL * 2;
  u16* xb   = (u16*)take(actBytes);
  u16* Wcat = (u16*)take(3 * wBytes);  // [3072][1024] = Wq;Wk;Wv
  u16* Wob  = (u16*)take(wBytes);
  u16* qb   = (u16*)take(actBytes);
  u16* kb   = (u16*)take(actBytes);
  u16* vt   = (u16*)take(actBytes);  // [B,H,DK,S]
  u16* ab   = (u16*)take(actBytes);
  float2* tab = (float2*)take((size_t)S_LEN * 32 * sizeof(float2));

  // Fused casts: x + 4 weight matrices in one launch.
  int ncast = NX4 + 4 * NW4;  // 3145728, exact multiple of 256
  cast_all<<<ncast / 256, 256, 0, stream>>>(x, Wq, Wk, Wv, Wo, xb, Wcat, Wob);

  // RoPE cos/sin table: 2048 x 32 pairs.
  rope_tab<<<(S_LEN * 32) / 256, 256, 0, stream>>>(pos, tab);

  // Fused QKV: [8192,1024] x [3072,1024]^T, RoPE fused in epilogue.
  gemm_p<<<dim3(BATCH * S_LEN / 128, 3 * DMODEL / 256), 512, 0, stream>>>(
      xb, Wcat, qb, kb, vt, nullptr, tab, 0);

  attn3<<<dim3(8, BATCH * NHEAD), 256, 0, stream>>>(qb, kb, vt, ab);

  gemm_p<<<dim3(BATCH * S_LEN / 128, DMODEL / 256), 512, 0, stream>>>(
      ab, Wob, nullptr, nullptr, nullptr, out, nullptr, 2);
}

// Round 7
// 263.244 us; speedup vs baseline: 1.0405x; 1.0405x over previous
//
#include <hip/hip_runtime.h>

// B=4, S=2048, D=1024, H=16, DK=64. RoPE (interleaved pairs) + causal MHA.
// R3: attention rewrite — no-max softmax, K=16 PV MFMA, merged q-tile pairs.
// R4: attn3 dbuf K/V prefetch + XCD-grouping block remap.
// R5: gemm 2-phase pipeline (dbuf LDS, prefetch-before-compute).
// R6: attn3 two q-tile pairs per block; fused cast_all.
// R7: gemm natural block order; RoPE fused into QKV epilogue (rope_tab).
// R8: attn3 32-col waves (neutral: attn is stall-bound, not LDS/VALU-bound).
// R9: counted-vmcnt gemm FAILED: BK=32 swizzle caused 6.3M bank conflicts,
//     16-MFMA phases too small, mis-ordered stage/barrier.
// R10 (this round): gemm_p rebuilt — BK=64 with the R5-proven ^(r&7)
// swizzle (0 conflicts), 3-slot LDS ring (144KB), 2 K-tiles prefetched
// ahead, vmcnt(6) counted wait (one tile in flight across the barrier,
// never 0 in-loop). Order: {vmcnt(6)+s_barrier fused asm} -> ds_reads ->
// stage(kt+2) -> 32 MFMA. WAR: slot(kt+2)=slot(kt-1) is staged only after
// the barrier that proves all waves finished reading it. RAW: own vmcnt(6)
// + barrier proves ALL waves' tile-kt loads landed. Tail: clamped restage
// keeps vmcnt counts uniform.

typedef unsigned short u16;
typedef unsigned int u32;
typedef __attribute__((ext_vector_type(8))) short bf16x8;
typedef __attribute__((ext_vector_type(4))) short bf16x4;
typedef __attribute__((ext_vector_type(4))) float f32x4;
typedef __attribute__((ext_vector_type(4))) unsigned short u16x4;

#define S_LEN 2048
#define DMODEL 1024
#define NHEAD 16
#define DKH 64
#define BATCH 4
#define NT 32  // S_LEN/64 key tiles
#define NX4 (BATCH * S_LEN * DMODEL / 4)  // 2097152
#define NW4 (DMODEL * DMODEL / 4)         // 262144 = 2^18

static __device__ __forceinline__ u16 f2bf(float f) {
  union { float f; u32 u; } v; v.f = f;
  u32 r = v.u + 0x7fffu + ((v.u >> 16) & 1u);  // RNE
  return (u16)(r >> 16);
}
#if __has_builtin(__builtin_amdgcn_cvt_pk_bf16_f32)
typedef __attribute__((ext_vector_type(2))) __bf16 bf2_t;
static __device__ __forceinline__ u32 pack2bf(float a, float b) {
  union { bf2_t h; u32 u; } cv;
  cv.h = __builtin_amdgcn_cvt_pk_bf16_f32(a, b);
  return cv.u;
}
#else
static __device__ __forceinline__ u32 pack2bf(float a, float b) {
  return (u32)f2bf(a) | ((u32)f2bf(b) << 16);
}
#endif
static __device__ __forceinline__ float fexp2(float x) {
#if __has_builtin(__builtin_amdgcn_exp2f)
  return __builtin_amdgcn_exp2f(x);
#else
  return exp2f(x);
#endif
}
static __device__ __forceinline__ f32x4 mfma16(bf16x8 a, bf16x8 b, f32x4 c) {
  return __builtin_amdgcn_mfma_f32_16x16x32_bf16(a, b, c, 0, 0, 0);
}
#if __has_builtin(__builtin_amdgcn_mfma_f32_16x16x16bf16_1k)
#define HAVE_MFMA_K16 1
static __device__ __forceinline__ f32x4 mfma16k16(bf16x4 a, bf16x4 b, f32x4 c) {
  return __builtin_amdgcn_mfma_f32_16x16x16bf16_1k(a, b, c, 0, 0, 0);
}
#else
#define HAVE_MFMA_K16 0
#endif
// Async global->LDS, 16B per lane. LDS dest = wave-uniform base + lane*16.
static __device__ __forceinline__ void glds16(const void* g, void* l) {
  __builtin_amdgcn_global_load_lds((const __attribute__((address_space(1))) u32*)g,
                                   (__attribute__((address_space(3))) u32*)l, 16, 0, 0);
}

// One fused cast pass: x (8M f32) + Wq,Wk,Wv -> Wcat + Wo -> Wob.
__global__ __launch_bounds__(256) void cast_all(const float* __restrict__ x,
                                                const float* __restrict__ Wq,
                                                const float* __restrict__ Wk,
                                                const float* __restrict__ Wv,
                                                const float* __restrict__ Wo,
                                                u16* __restrict__ xb,
                                                u16* __restrict__ Wcat,
                                                u16* __restrict__ Wob) {
  int i = blockIdx.x * 256 + threadIdx.x;
  const float* s;
  u16* d;
  if (i < NX4) {
    s = x + (size_t)i * 4;
    d = xb + (size_t)i * 4;
  } else {
    int j = i - NX4;
    int r = j >> 18;
    int off = j & (NW4 - 1);
    const float* W = r == 0 ? Wq : r == 1 ? Wk : r == 2 ? Wv : Wo;
    s = W + (size_t)off * 4;
    d = (r < 3 ? Wcat + (size_t)r * DMODEL * DMODEL : Wob) + (size_t)off * 4;
  }
  u16x4 o;
  o.x = f2bf(s[0]); o.y = f2bf(s[1]); o.z = f2bf(s[2]); o.w = f2bf(s[3]);
  *(u16x4*)d = o;
}

// cos/sin table for RoPE: tab[s*32+p] = {cos, sin}(pos[s] * 10000^(-2p/64)).
__global__ __launch_bounds__(256) void rope_tab(const int* __restrict__ pos,
                                                float2* __restrict__ tab) {
  int i = blockIdx.x * 256 + threadIdx.x;  // over 2048*32
  int s = i >> 5, p = i & 31;
  float ph = (float)pos[s] * powf(10000.0f, -(float)(2 * p) / 64.0f);
  float sn, cs;
  sincosf(ph, &sn, &cs);
  tab[i] = make_float2(cs, sn);
}

// Counted-vmcnt pipelined GEMM. C[m,n] = sum_k A[m,k]*W[n,k].
// Tile 128x256, 512 threads = 8 waves (2M x 4N), per-wave 64x64 output.
// K in 16 tiles of 64, 3-slot LDS ring (144KB), 2 tiles prefetched ahead.
// Per iter: {vmcnt(6)+barrier} -> 16 ds_read_b128 -> stage(kt+2) [6 glds]
// -> 32 MFMA (setprio). Swizzle: 8-u16 chunk ch of row r stored at ch^(r&7)
// (R5-proven, 0 conflicts); glds dest linear, source col pre-swizzled.
// mode 0: QKV epilogue with fused RoPE; mode 2: fp32 store to of.
__global__ __launch_bounds__(512, 2) void gemm_p(const u16* __restrict__ A,
                                                 const u16* __restrict__ W,
                                                 u16* __restrict__ oq,
                                                 u16* __restrict__ ok,
                                                 u16* __restrict__ ov,
                                                 float* __restrict__ of,
                                                 const float2* __restrict__ tab,
                                                 int mode) {
  __shared__ __attribute__((aligned(16))) u16 As[3][128 * 64];  // 48 KB
  __shared__ __attribute__((aligned(16))) u16 Bs[3][256 * 64];  // 96 KB
  const int m0 = blockIdx.x * 128, n0 = blockIdx.y * 256;
  const int tid = threadIdx.x, lane = tid & 63, wave = tid >> 6;
  const int quad = lane >> 4, c = lane & 15;
  const int wm = (wave & 1) * 64, wn = (wave >> 1) * 64;
  const int ls = lane >> 3, lc = lane & 7;

  // stage K-tile kt (64 cols) into ring slot: A 2 instr, B 4 instr / thread
  auto stageA = [&](int slot, int kt) {
#pragma unroll
    for (int i = 0; i < 2; ++i) {
      int g = wave + i * 8;       // 16 groups x 8 rows = 128
      int r = g * 8 + ls;
      glds16(&A[(size_t)(m0 + r) * DMODEL + kt * 64 + 8 * (lc ^ (r & 7))],
             &As[slot][g * 512]);
    }
  };
  auto stageB = [&](int slot, int kt) {
#pragma unroll
    for (int i = 0; i < 4; ++i) {
      int g = wave + i * 8;       // 32 groups x 8 rows = 256
      int r = g * 8 + ls;
      glds16(&W[(size_t)(n0 + r) * DMODEL + kt * 64 + 8 * (lc ^ (r & 7))],
             &Bs[slot][g * 512]);
    }
  };

  f32x4 acc[4][4] = {};
  // prologue: tiles 0,1 in flight (12 vmem instrs/wave)
  stageA(0, 0); stageB(0, 0);
  stageA(1, 1); stageB(1, 1);
#pragma unroll 1
  for (int kt = 0; kt < 16; ++kt) {
    const int slot = kt % 3;
    const int sslot = (kt + 2) % 3;
    const int st = (kt + 2 <= 15) ? kt + 2 : 15;  // tail: clamped restage
    // own vmcnt(6): my tile-kt 6 loads done (tile kt+1's 6 stay in flight);
    // barrier: ALL waves passed their vmcnt -> slot kt fully written.
    // Fused asm + memory clobber: no LDS read or glds crosses this point.
    asm volatile("s_waitcnt vmcnt(6)\n\ts_barrier" ::: "memory");
    bf16x8 af[2][4], bfr[2][4];
#pragma unroll
    for (int t = 0; t < 2; ++t) {
#pragma unroll
      for (int mf = 0; mf < 4; ++mf) {
        int r = wm + mf * 16 + c;
        af[t][mf] = *(const bf16x8*)&As[slot][r * 64 + 8 * ((t * 4 + quad) ^ (r & 7))];
      }
#pragma unroll
      for (int nf = 0; nf < 4; ++nf) {
        int r = wn + nf * 16 + c;
        bfr[t][nf] = *(const bf16x8*)&Bs[slot][r * 64 + 8 * ((t * 4 + quad) ^ (r & 7))];
      }
    }
    // stage tile kt+2 into slot (kt-1)%3: safe, all reads of it fenced by
    // the barrier above. Issued before MFMA so HBM latency hides under it.
    stageA(sslot, st);
    stageB(sslot, st);
    __builtin_amdgcn_s_setprio(1);
#pragma unroll
    for (int t = 0; t < 2; ++t)
#pragma unroll
      for (int mf = 0; mf < 4; ++mf)
#pragma unroll
        for (int nf = 0; nf < 4; ++nf)
          acc[mf][nf] = mfma16(af[t][mf], bfr[t][nf], acc[mf][nf]);
    __builtin_amdgcn_s_setprio(0);
  }

#pragma unroll
  for (int mf = 0; mf < 4; ++mf) {
    int mrow = m0 + wm + mf * 16 + quad * 4;
#pragma unroll
    for (int nf = 0; nf < 4; ++nf) {
      int n = n0 + wn + nf * 16 + c;
      f32x4 v = acc[mf][nf];
      if (mode == 2) {
#pragma unroll
        for (int r = 0; r < 4; ++r) of[(size_t)(mrow + r) * DMODEL + n] = v[r];
      } else if (n < 2 * DMODEL) {
        // fused RoPE: pair partner (d^1) is in neighbor lane (c parity == n
        // parity: n0/wn/nf*16 all even). Wave-uniform branch region.
        const bool isq = n < DMODEL;
        const int p = (n & 63) >> 1;  // pair index within head
        const bool odd = n & 1;
        u16* dst = isq ? oq : ok;
        const int ncol = n & (DMODEL - 1);
#pragma unroll
        for (int r = 0; r < 4; ++r) {
          float v1 = v[r];
          float v2 = __shfl_xor(v1, 1);
          float x1 = odd ? v2 : v1;
          float x2 = odd ? v1 : v2;
          int s = (mrow + r) & (S_LEN - 1);
          float2 t2 = tab[s * 32 + p];
          float rv = odd ? (x1 * t2.y + x2 * t2.x) : (x1 * t2.x - x2 * t2.y);
          if (isq) rv *= 0.18033688011112042f;  // 0.125 * log2(e)
          dst[(size_t)(mrow + r) * DMODEL + ncol] = f2bf(rv);
        }
      } else {
        int nn = n - 2 * DMODEL;
        int h = nn >> 6, d = nn & 63;
        int b = mrow >> 11, s = mrow & (S_LEN - 1);
        u16x4 p4;
        p4.x = f2bf(v[0]); p4.y = f2bf(v[1]); p4.z = f2bf(v[2]); p4.w = f2bf(v[3]);
        *(u16x4*)&ov[((size_t)(b * NHEAD + h) * DKH + d) * S_LEN + s] = p4;
      }
    }
  }
}

// Flash attention, S^T formulation, no-max softmax. (R8 structure.)
// Grid (8, B*H), 256 threads (4 waves). Block owns TWO merged q-tile pairs:
//   waves 0-1: pair A = (2x, 31-2x); waves 2-3: pair B = (2x+1, 30-2x).
// Each wave owns 32 q-cols (col-half = wave&1) as two 16-col groups. XCD
// remap keeps each (b,h)'s 8 blocks on one XCD. setprio around MFMA.
__global__ __launch_bounds__(256, 2) void attn3(const u16* __restrict__ qb,
                                                const u16* __restrict__ kb,
                                                const u16* __restrict__ vt,
                                                u16* __restrict__ ab) {
  __shared__ __attribute__((aligned(16))) u16 Ks[2][64 * 64];  // [key][d] swizzled
  __shared__ __attribute__((aligned(16))) u16 Vs[2][64 * 64];  // [d][key] swizzled
  const int L = blockIdx.x + 8 * blockIdx.y;
  const int xcd = L & 7, slot = L >> 3;   // slot in [0,64)
  const int bhl = slot >> 3;              // local head in [0,8)
  const int xs = slot & 7;
  const int x = (bhl & 4) ? 7 - xs : xs;  // complementary-x tail balance
  const int bh = xcd * 8 + bhl;
  const int b = bh >> 4, h = bh & 15;
  const int tid = threadIdx.x, lane = tid & 63, wave = tid >> 6;
  const int g = wave >> 1;   // 0: pair A, 1: pair B
  const int wh = wave & 1;   // 32-col half within tile
  const int quad = lane >> 4, c = lane & 15;
  const int ls = lane >> 3, lc = lane & 7;
  const int wq0 = wh * 32;   // base q-col of this wave's 32 cols
  const int qtl = 2 * x + g, qth = 31 - 2 * x - g;
  const int J = 31 - 2 * x;  // loop bound = pair A's qt2
  const float NEG = -3.0e38f;

  // qf[t][cg][dh]: q fragment for tile t, 16-col group cg, d-half dh
  bf16x8 qf[2][2][2];
#pragma unroll
  for (int t = 0; t < 2; ++t)
#pragma unroll
    for (int cg = 0; cg < 2; ++cg) {
      int qrow = (t ? qth : qtl) * 64 + wq0 + cg * 16 + c;
      const u16* qp = qb + (size_t)(b * S_LEN + qrow) * DMODEL + h * DKH;
      qf[t][cg][0] = *(const bf16x8*)&qp[quad * 8];
      qf[t][cg][1] = *(const bf16x8*)&qp[32 + quad * 8];
    }
  float li[2][2] = {};
  f32x4 od[2][2][4] = {};

  // stage tile j into buffer buf: 4 waves x 16 rows each (K and V), no wait
  auto stage = [&](int buf, int j) {
#pragma unroll
    for (int i = 0; i < 2; ++i) {
      int rb = wave * 16 + i * 8;
      int r = rb + ls;
      int col = 8 * (lc ^ (r & 7));
      glds16(&kb[(size_t)(b * S_LEN + j * 64 + r) * DMODEL + h * DKH + col],
             &Ks[buf][rb * 64]);
      glds16(&vt[((size_t)bh * DKH + r) * S_LEN + j * 64 + col],
             &Vs[buf][rb * 64]);
    }
  };

  // one q-tile application (32 cols = 2 col-groups) against buffer cur
  auto apply = [&](int t, int cur, bool diag) {
    f32x4 sc[2][4];
    __builtin_amdgcn_s_setprio(1);
#pragma unroll
    for (int kbi = 0; kbi < 4; ++kbi) {
      int r = kbi * 16 + c;
      bf16x8 k0 = *(const bf16x8*)&Ks[cur][r * 64 + 8 * (quad ^ (r & 7))];
      bf16x8 k1 = *(const bf16x8*)&Ks[cur][r * 64 + 8 * ((4 + quad) ^ (r & 7))];
#pragma unroll
      for (int cg = 0; cg < 2; ++cg) {
        f32x4 a = {};
        a = mfma16(k0, qf[t][cg][0], a);
        a = mfma16(k1, qf[t][cg][1], a);
        sc[cg][kbi] = a;  // already log2-domain (q pre-scaled)
      }
    }
    __builtin_amdgcn_s_setprio(0);
    if (diag) {
#pragma unroll
      for (int cg = 0; cg < 2; ++cg)
#pragma unroll
        for (int kbi = 0; kbi < 4; ++kbi)
#pragma unroll
          for (int r = 0; r < 4; ++r)
            if (kbi * 16 + quad * 4 + r > wq0 + cg * 16 + c) sc[cg][kbi][r] = NEG;
    }
    float rs[2] = {0.f, 0.f};
#pragma unroll
    for (int cg = 0; cg < 2; ++cg)
#pragma unroll
      for (int kbi = 0; kbi < 4; ++kbi)
#pragma unroll
        for (int r = 0; r < 4; ++r) {
          float p = fexp2(sc[cg][kbi][r]);
          sc[cg][kbi][r] = p;
          rs[cg] += p;
        }
#pragma unroll
    for (int cg = 0; cg < 2; ++cg) {
      float v = rs[cg];
      v += __shfl_xor(v, 16);
      v += __shfl_xor(v, 32);
      li[t][cg] += v;
    }
#if HAVE_MFMA_K16
    // pkv[cg][kbi] = keys kbi*16+quad*4+{0..3} for q-col c == 16x16x16 B-frag
    bf16x4 pkv[2][4];
#pragma unroll
    for (int cg = 0; cg < 2; ++cg)
#pragma unroll
      for (int kbi = 0; kbi < 4; ++kbi) {
        union { u32 w[2]; bf16x4 v; } pk;
        pk.w[0] = pack2bf(sc[cg][kbi][0], sc[cg][kbi][1]);
        pk.w[1] = pack2bf(sc[cg][kbi][2], sc[cg][kbi][3]);
        pkv[cg][kbi] = pk.v;
      }
    __builtin_amdgcn_s_setprio(1);
#pragma unroll
    for (int db = 0; db < 4; ++db) {
      int r = db * 16 + c;
#pragma unroll
      for (int kbi = 0; kbi < 4; ++kbi) {
        int g2 = kbi * 2 + (quad >> 1);
        bf16x4 vf = *(const bf16x4*)&Vs[cur][r * 64 + 8 * (g2 ^ (r & 7)) + (quad & 1) * 4];
        od[t][0][db] = mfma16k16(vf, pkv[0][kbi], od[t][0][db]);
        od[t][1][db] = mfma16k16(vf, pkv[1][kbi], od[t][1][db]);
      }
    }
    __builtin_amdgcn_s_setprio(0);
#else
    // fallback: shuffle P^T into K=32 B-frag layout, per col-group
#pragma unroll
    for (int cg = 0; cg < 2; ++cg) {
      u32 pk[4][2];
#pragma unroll
      for (int kbi = 0; kbi < 4; ++kbi) {
        pk[kbi][0] = pack2bf(sc[cg][kbi][0], sc[cg][kbi][1]);
        pk[kbi][1] = pack2bf(sc[cg][kbi][2], sc[cg][kbi][3]);
      }
      const int s0 = ((quad & 1) * 2) * 16 + c;
      const int s1 = s0 + 16;
      const bool hi = quad >= 2;
#pragma unroll
      for (int base = 0; base < 2; ++base) {
        u32 e0 = __shfl(pk[base * 2][0], s0);
        u32 e1 = __shfl(pk[base * 2][1], s0);
        u32 e2 = __shfl(pk[base * 2][0], s1);
        u32 e3 = __shfl(pk[base * 2][1], s1);
        u32 o0 = __shfl(pk[base * 2 + 1][0], s0);
        u32 o1 = __shfl(pk[base * 2 + 1][1], s0);
        u32 o2 = __shfl(pk[base * 2 + 1][0], s1);
        u32 o3 = __shfl(pk[base * 2 + 1][1], s1);
        union { u32 w[4]; bf16x8 v; } pf;
        pf.w[0] = hi ? o0 : e0;
        pf.w[1] = hi ? o1 : e1;
        pf.w[2] = hi ? o2 : e2;
        pf.w[3] = hi ? o3 : e3;
#pragma unroll
        for (int db = 0; db < 4; ++db) {
          int r = db * 16 + c;
          bf16x8 vf = *(const bf16x8*)&Vs[cur][r * 64 + 8 * ((base * 4 + quad) ^ (c & 7))];
          od[t][cg][db] = mfma16(vf, pf.v, od[t][cg][db]);
        }
      }
    }
#endif
  };

  // prologue: stage tile 0 into buffer 0, wait (syncthreads drains vmcnt)
  stage(0, 0);
  __syncthreads();
#pragma unroll 1
  for (int j = 0; j <= J; ++j) {
    int cur = j & 1;
    if (j < J) stage(cur ^ 1, j + 1);  // prefetch next tile, no wait
    if (j <= qtl) apply(0, cur, j == qtl);
    if (j <= qth) apply(1, cur, j == qth);
    __syncthreads();  // vmcnt(0)+lgkmcnt(0)+barrier: next buffer ready
  }

#pragma unroll
  for (int t = 0; t < 2; ++t)
#pragma unroll
    for (int cg = 0; cg < 2; ++cg) {
      float inv = 1.0f / li[t][cg];
      int qrow = (t ? qth : qtl) * 64 + wq0 + cg * 16 + c;
      u16* op = ab + (size_t)(b * S_LEN + qrow) * DMODEL + h * DKH;
#pragma unroll
      for (int db = 0; db < 4; ++db) {
        u16x4 o4;
        o4.x = f2bf(od[t][cg][db][0] * inv);
        o4.y = f2bf(od[t][cg][db][1] * inv);
        o4.z = f2bf(od[t][cg][db][2] * inv);
        o4.w = f2bf(od[t][cg][db][3] * inv);
        *(u16x4*)&op[db * 16 + quad * 4] = o4;
      }
    }
}

extern "C" void kernel_launch(void* const* d_in, const int* in_sizes, int n_in,
                              void* d_out, int out_size, void* d_ws, size_t ws_size,
                              hipStream_t stream) {
  const float* x = (const float*)d_in[0];
  const int* pos = (const int*)d_in[1];
  const float* Wq = (const float*)d_in[2];
  const float* Wk = (const float*)d_in[3];
  const float* Wv = (const float*)d_in[4];
  const float* Wo = (const float*)d_in[5];
  float* out = (float*)d_out;

  char* w = (char*)d_ws;
  size_t o = 0;
  auto take = [&](size_t nbytes) {
    char* p = w + o;
    o += (nbytes + 255) & ~(size_t)255;
    return p;
  };
  const size_t actBytes = (size_t)BATCH * S_LEN * DMODEL * 2;
  const size_t wBytes = (size_t)DMODEL * DMODEL * 2;
  u16* xb   = (u16*)take(actBytes);
  u16* Wcat = (u16*)take(3 * wBytes);  // [3072][1024] = Wq;Wk;Wv
  u16* Wob  = (u16*)take(wBytes);
  u16* qb   = (u16*)take(actBytes);
  u16* kb   = (u16*)take(actBytes);
  u16* vt   = (u16*)take(actBytes);  // [B,H,DK,S]
  u16* ab   = (u16*)take(actBytes);
  float2* tab = (float2*)take((size_t)S_LEN * 32 * sizeof(float2));

  // Fused casts: x + 4 weight matrices in one launch.
  int ncast = NX4 + 4 * NW4;  // 3145728, exact multiple of 256
  cast_all<<<ncast / 256, 256, 0, stream>>>(x, Wq, Wk, Wv, Wo, xb, Wcat, Wob);

  // RoPE cos/sin table: 2048 x 32 pairs.
  rope_tab<<<(S_LEN * 32) / 256, 256, 0, stream>>>(pos, tab);

  // Fused QKV: [8192,1024] x [3072,1024]^T, RoPE fused in epilogue.
  gemm_p<<<dim3(BATCH * S_LEN / 128, 3 * DMODEL / 256), 512, 0, stream>>>(
      xb, Wcat, qb, kb, vt, nullptr, tab, 0);

  attn3<<<dim3(8, BATCH * NHEAD), 256, 0, stream>>>(qb, kb, vt, ab);

  gemm_p<<<dim3(BATCH * S_LEN / 128, DMODEL / 256), 512, 0, stream>>>(
      ab, Wob, nullptr, nullptr, nullptr, out, nullptr, 2);
}

// Round 8
// 253.413 us; speedup vs baseline: 1.0809x; 1.0388x over previous
//
#include <hip/hip_runtime.h>

// B=4, S=2048, D=1024, H=16, DK=64. RoPE (interleaved pairs) + causal MHA.
// R3: attention rewrite — no-max softmax, K=16 PV MFMA, merged q-tile pairs.
// R4: attn3 dbuf K/V prefetch + XCD-grouping block remap.
// R5: gemm 2-phase pipeline (dbuf LDS, prefetch-before-compute).
// R6: attn3 two q-tile pairs per block; fused cast_all.
// R7: gemm natural block order; RoPE fused into QKV epilogue (rope_tab).
// R8: attn3 32-col waves (neutral: attn is stall-bound, not LDS/VALU-bound).
// R9/R10: counted-vmcnt gemm attempts REGRESSED (R9: bad swizzle + tiny
//   phases; R10: 144KB LDS -> 1 block/CU killed the implicit block overlap
//   that makes the 2-phase work). Lesson: keep 2 blocks/CU.
// R11 (this round):
//  - gemm reverted to the R7 2-phase gemm128 (known 79us QKV, 0 conflicts).
//  - attn3 KVBLK 64->128: stage 128 keys per barrier round (64KB LDS, still
//    2 blocks/CU), apply both 64-key sub-tiles from one buffer -> barrier
//    count HALVED (attn is stall-bound on the stage->barrier chain).
//  - rope_tab merged into cast_all tail blocks (one fewer launch).

typedef unsigned short u16;
typedef unsigned int u32;
typedef __attribute__((ext_vector_type(8))) short bf16x8;
typedef __attribute__((ext_vector_type(4))) short bf16x4;
typedef __attribute__((ext_vector_type(4))) float f32x4;
typedef __attribute__((ext_vector_type(4))) unsigned short u16x4;

#define S_LEN 2048
#define DMODEL 1024
#define NHEAD 16
#define DKH 64
#define BATCH 4
#define NT 32  // S_LEN/64 key tiles
#define NX4 (BATCH * S_LEN * DMODEL / 4)  // 2097152
#define NW4 (DMODEL * DMODEL / 4)         // 262144 = 2^18
#define NTAB (S_LEN * 32)                 // 65536 rope table entries

static __device__ __forceinline__ u16 f2bf(float f) {
  union { float f; u32 u; } v; v.f = f;
  u32 r = v.u + 0x7fffu + ((v.u >> 16) & 1u);  // RNE
  return (u16)(r >> 16);
}
#if __has_builtin(__builtin_amdgcn_cvt_pk_bf16_f32)
typedef __attribute__((ext_vector_type(2))) __bf16 bf2_t;
static __device__ __forceinline__ u32 pack2bf(float a, float b) {
  union { bf2_t h; u32 u; } cv;
  cv.h = __builtin_amdgcn_cvt_pk_bf16_f32(a, b);
  return cv.u;
}
#else
static __device__ __forceinline__ u32 pack2bf(float a, float b) {
  return (u32)f2bf(a) | ((u32)f2bf(b) << 16);
}
#endif
static __device__ __forceinline__ float fexp2(float x) {
#if __has_builtin(__builtin_amdgcn_exp2f)
  return __builtin_amdgcn_exp2f(x);
#else
  return exp2f(x);
#endif
}
static __device__ __forceinline__ f32x4 mfma16(bf16x8 a, bf16x8 b, f32x4 c) {
  return __builtin_amdgcn_mfma_f32_16x16x32_bf16(a, b, c, 0, 0, 0);
}
#if __has_builtin(__builtin_amdgcn_mfma_f32_16x16x16bf16_1k)
#define HAVE_MFMA_K16 1
static __device__ __forceinline__ f32x4 mfma16k16(bf16x4 a, bf16x4 b, f32x4 c) {
  return __builtin_amdgcn_mfma_f32_16x16x16bf16_1k(a, b, c, 0, 0, 0);
}
#else
#define HAVE_MFMA_K16 0
#endif
// Async global->LDS, 16B per lane. LDS dest = wave-uniform base + lane*16.
static __device__ __forceinline__ void glds16(const void* g, void* l) {
  __builtin_amdgcn_global_load_lds((const __attribute__((address_space(1))) u32*)g,
                                   (__attribute__((address_space(3))) u32*)l, 16, 0, 0);
}

// One fused pass: x + Wq,Wk,Wv -> Wcat + Wo -> Wob + RoPE cos/sin table.
__global__ __launch_bounds__(256) void cast_all(const float* __restrict__ x,
                                                const float* __restrict__ Wq,
                                                const float* __restrict__ Wk,
                                                const float* __restrict__ Wv,
                                                const float* __restrict__ Wo,
                                                u16* __restrict__ xb,
                                                u16* __restrict__ Wcat,
                                                u16* __restrict__ Wob,
                                                const int* __restrict__ pos,
                                                float2* __restrict__ tab) {
  int i = blockIdx.x * 256 + threadIdx.x;
  const float* s;
  u16* d;
  if (i < NX4) {
    s = x + (size_t)i * 4;
    d = xb + (size_t)i * 4;
  } else if (i < NX4 + 4 * NW4) {
    int j = i - NX4;
    int r = j >> 18;
    int off = j & (NW4 - 1);
    const float* W = r == 0 ? Wq : r == 1 ? Wk : r == 2 ? Wv : Wo;
    s = W + (size_t)off * 4;
    d = (r < 3 ? Wcat + (size_t)r * DMODEL * DMODEL : Wob) + (size_t)off * 4;
  } else {
    // rope table tail: tab[s*32+p] = {cos,sin}(pos[s] * 10000^(-2p/64))
    int j = i - (NX4 + 4 * NW4);  // [0, NTAB)
    int sq = j >> 5, p = j & 31;
    float ph = (float)pos[sq] * powf(10000.0f, -(float)(2 * p) / 64.0f);
    float sn, cs;
    sincosf(ph, &sn, &cs);
    tab[j] = make_float2(cs, sn);
    return;
  }
  u16x4 o;
  o.x = f2bf(s[0]); o.y = f2bf(s[1]); o.z = f2bf(s[2]); o.w = f2bf(s[3]);
  *(u16x4*)d = o;
}

// C[m,n] = sum_k A[m,k] * W[n,k]. 128x128 tile, BK=64, glds staging,
// 2-phase double-buffered pipeline (R7-proven): stage tile kt+1 into buf^1
// BEFORE the MFMA phase on buf; single __syncthreads per K-step. 64KB LDS
// -> 2 blocks/CU, whose implicit overlap covers the barrier drains.
// mode 0: QKV epilogue with fused RoPE; mode 2: fp32 store to of.
__global__ __launch_bounds__(256) void gemm128(const u16* __restrict__ A,
                                               const u16* __restrict__ W,
                                               u16* __restrict__ oq,
                                               u16* __restrict__ ok,
                                               u16* __restrict__ ov,
                                               float* __restrict__ of,
                                               const float2* __restrict__ tab,
                                               int mode) {
  __shared__ __attribute__((aligned(16))) u16 As[2][128 * 64];
  __shared__ __attribute__((aligned(16))) u16 Bs[2][128 * 64];
  const int m0 = blockIdx.x * 128, n0 = blockIdx.y * 128;
  const int tid = threadIdx.x, lane = tid & 63, wave = tid >> 6;
  const int quad = lane >> 4, c = lane & 15;
  const int wm = (wave & 1) * 64, wn = (wave >> 1) * 64;
  const int ls = lane >> 3, lc = lane & 7;

  auto stage = [&](int buf, int ko) {
#pragma unroll
    for (int i = 0; i < 4; ++i) {
      int rb = i * 32 + wave * 8;
      int r = rb + ls;
      int kA = ko + 8 * (lc ^ (r & 7));
      glds16(&A[(size_t)(m0 + r) * DMODEL + kA], &As[buf][rb * 64]);
      glds16(&W[(size_t)(n0 + r) * DMODEL + kA], &Bs[buf][rb * 64]);
    }
  };

  f32x4 acc[4][4] = {};
  stage(0, 0);
  __syncthreads();
#pragma unroll 1
  for (int kt = 0; kt < DMODEL / 64; ++kt) {
    const int cur = kt & 1;
    if (kt < DMODEL / 64 - 1) stage(cur ^ 1, (kt + 1) * 64);  // prefetch, no wait
#pragma unroll
    for (int t = 0; t < 2; ++t) {
      bf16x8 af[4], bfr[4];
#pragma unroll
      for (int mb = 0; mb < 4; ++mb) {
        int r = wm + mb * 16 + c;
        af[mb] = *(const bf16x8*)&As[cur][r * 64 + 8 * ((t * 4 + quad) ^ (r & 7))];
      }
#pragma unroll
      for (int nb = 0; nb < 4; ++nb) {
        int r = wn + nb * 16 + c;
        bfr[nb] = *(const bf16x8*)&Bs[cur][r * 64 + 8 * ((t * 4 + quad) ^ (r & 7))];
      }
#pragma unroll
      for (int mb = 0; mb < 4; ++mb)
#pragma unroll
        for (int nb = 0; nb < 4; ++nb)
          acc[mb][nb] = mfma16(af[mb], bfr[nb], acc[mb][nb]);
    }
    __syncthreads();  // vmcnt(0)+barrier: prefetched buffer ready for kt+1
  }
#pragma unroll
  for (int mb = 0; mb < 4; ++mb) {
    int mrow = m0 + wm + mb * 16 + quad * 4;
#pragma unroll
    for (int nb = 0; nb < 4; ++nb) {
      int n = n0 + wn + nb * 16 + c;
      f32x4 v = acc[mb][nb];
      if (mode == 2) {
#pragma unroll
        for (int r = 0; r < 4; ++r) of[(size_t)(mrow + r) * DMODEL + n] = v[r];
      } else if (n < 2 * DMODEL) {
        // fused RoPE: pair partner (d^1) is in neighbor lane (c parity == n
        // parity: n0/wn/nb*16 all even). Wave-uniform branch region.
        const bool isq = n < DMODEL;
        const int p = (n & 63) >> 1;  // pair index within head
        const bool odd = n & 1;
        u16* dst = isq ? oq : ok;
        const int ncol = n & (DMODEL - 1);
#pragma unroll
        for (int r = 0; r < 4; ++r) {
          float v1 = v[r];
          float v2 = __shfl_xor(v1, 1);
          float x1 = odd ? v2 : v1;
          float x2 = odd ? v1 : v2;
          int s = (mrow + r) & (S_LEN - 1);
          float2 t2 = tab[s * 32 + p];
          float rv = odd ? (x1 * t2.y + x2 * t2.x) : (x1 * t2.x - x2 * t2.y);
          if (isq) rv *= 0.18033688011112042f;  // 0.125 * log2(e)
          dst[(size_t)(mrow + r) * DMODEL + ncol] = f2bf(rv);
        }
      } else {
        int nn = n - 2 * DMODEL;
        int h = nn >> 6, d = nn & 63;
        int b = mrow >> 11, s = mrow & (S_LEN - 1);
        u16x4 p4;
        p4.x = f2bf(v[0]); p4.y = f2bf(v[1]); p4.z = f2bf(v[2]); p4.w = f2bf(v[3]);
        *(u16x4*)&ov[((size_t)(b * NHEAD + h) * DKH + d) * S_LEN + s] = p4;
      }
    }
  }
}

// Flash attention, S^T formulation, no-max softmax.
// Grid (8, B*H), 256 threads (4 waves). Block owns TWO merged q-tile pairs:
//   waves 0-1: pair A = (2x, 31-2x); waves 2-3: pair B = (2x+1, 30-2x).
// Each wave owns 32 q-cols (two 16-col groups). R11: K/V staged in 128-key
// SUPER-TILES (Ks[2][128x64], Vs[2][64x128], 64KB, 2 blocks/CU): one
// stage+barrier round feeds TWO 64-key sub-tile applies per pair -> barrier
// count halved (attn is stall-bound on the stage->barrier chain, R8).
// V rows are 256B: 16-chunk XOR swizzle ^(r&15) (2-way max = free).
// XCD remap keeps each (b,h)'s 8 blocks on one XCD. setprio around MFMA.
__global__ __launch_bounds__(256, 2) void attn3(const u16* __restrict__ qb,
                                                const u16* __restrict__ kb,
                                                const u16* __restrict__ vt,
                                                u16* __restrict__ ab) {
  __shared__ __attribute__((aligned(16))) u16 Ks[2][128 * 64];  // [key][d] swz
  __shared__ __attribute__((aligned(16))) u16 Vs[2][64 * 128];  // [d][key] swz
  const int L = blockIdx.x + 8 * blockIdx.y;
  const int xcd = L & 7, slot = L >> 3;   // slot in [0,64)
  const int bhl = slot >> 3;              // local head in [0,8)
  const int xs = slot & 7;
  const int x = (bhl & 4) ? 7 - xs : xs;  // complementary-x tail balance
  const int bh = xcd * 8 + bhl;
  const int b = bh >> 4, h = bh & 15;
  const int tid = threadIdx.x, lane = tid & 63, wave = tid >> 6;
  const int g = wave >> 1;   // 0: pair A, 1: pair B
  const int wh = wave & 1;   // 32-col half within tile
  const int quad = lane >> 4, c = lane & 15;
  const int ls = lane >> 3, lc = lane & 7;    // K staging: 8 rows x 8 chunks
  const int ls2 = lane >> 4, lc2 = lane & 15; // V staging: 4 rows x 16 chunks
  const int wq0 = wh * 32;   // base q-col of this wave's 32 cols
  const int qtl = 2 * x + g, qth = 31 - 2 * x - g;
  const int J = 31 - 2 * x;      // max key tile (odd)
  const int NS = (J + 1) >> 1;   // 128-key super-tiles
  const float NEG = -3.0e38f;

  // qf[t][cg][dh]: q fragment for tile t, 16-col group cg, d-half dh
  bf16x8 qf[2][2][2];
#pragma unroll
  for (int t = 0; t < 2; ++t)
#pragma unroll
    for (int cg = 0; cg < 2; ++cg) {
      int qrow = (t ? qth : qtl) * 64 + wq0 + cg * 16 + c;
      const u16* qp = qb + (size_t)(b * S_LEN + qrow) * DMODEL + h * DKH;
      qf[t][cg][0] = *(const bf16x8*)&qp[quad * 8];
      qf[t][cg][1] = *(const bf16x8*)&qp[32 + quad * 8];
    }
  float li[2][2] = {};
  f32x4 od[2][2][4] = {};

  // stage 128-key super-tile jj into buffer buf (8 glds/wave, no wait)
  auto stage = [&](int buf, int jj) {
    // K: 128 rows (keys) x 64 d; wave stages 32 rows as 4 glds of 8 rows
#pragma unroll
    for (int i = 0; i < 4; ++i) {
      int rb = wave * 32 + i * 8;
      int r = rb + ls;
      glds16(&kb[(size_t)(b * S_LEN + jj * 128 + r) * DMODEL + h * DKH +
                 8 * (lc ^ (r & 7))],
             &Ks[buf][rb * 64]);
    }
    // V: 64 rows (d) x 128 keys; wave stages 16 rows as 4 glds of 4 rows
#pragma unroll
    for (int i = 0; i < 4; ++i) {
      int rb = wave * 16 + i * 4;
      int r = rb + ls2;
      glds16(&vt[((size_t)bh * DKH + r) * S_LEN + jj * 128 +
                 8 * (lc2 ^ (r & 15))],
             &Vs[buf][rb * 128]);
    }
  };

  // one q-tile application against 64-key sub-tile sub of buffer cur
  auto apply = [&](int t, int cur, int sub, bool diag) {
    f32x4 sc[2][4];
    __builtin_amdgcn_s_setprio(1);
#pragma unroll
    for (int kbi = 0; kbi < 4; ++kbi) {
      int r = sub * 64 + kbi * 16 + c;  // r&7 == c&7
      bf16x8 k0 = *(const bf16x8*)&Ks[cur][r * 64 + 8 * (quad ^ (r & 7))];
      bf16x8 k1 = *(const bf16x8*)&Ks[cur][r * 64 + 8 * ((4 + quad) ^ (r & 7))];
#pragma unroll
      for (int cg = 0; cg < 2; ++cg) {
        f32x4 a = {};
        a = mfma16(k0, qf[t][cg][0], a);
        a = mfma16(k1, qf[t][cg][1], a);
        sc[cg][kbi] = a;  // already log2-domain (q pre-scaled)
      }
    }
    __builtin_amdgcn_s_setprio(0);
    if (diag) {
#pragma unroll
      for (int cg = 0; cg < 2; ++cg)
#pragma unroll
        for (int kbi = 0; kbi < 4; ++kbi)
#pragma unroll
          for (int r = 0; r < 4; ++r)
            if (kbi * 16 + quad * 4 + r > wq0 + cg * 16 + c) sc[cg][kbi][r] = NEG;
    }
    float rs[2] = {0.f, 0.f};
#pragma unroll
    for (int cg = 0; cg < 2; ++cg)
#pragma unroll
      for (int kbi = 0; kbi < 4; ++kbi)
#pragma unroll
        for (int r = 0; r < 4; ++r) {
          float p = fexp2(sc[cg][kbi][r]);
          sc[cg][kbi][r] = p;
          rs[cg] += p;
        }
#pragma unroll
    for (int cg = 0; cg < 2; ++cg) {
      float v = rs[cg];
      v += __shfl_xor(v, 16);
      v += __shfl_xor(v, 32);
      li[t][cg] += v;
    }
#if HAVE_MFMA_K16
    // pkv[cg][kbi] = keys kbi*16+quad*4+{0..3} for q-col c == 16x16x16 B-frag
    bf16x4 pkv[2][4];
#pragma unroll
    for (int cg = 0; cg < 2; ++cg)
#pragma unroll
      for (int kbi = 0; kbi < 4; ++kbi) {
        union { u32 w[2]; bf16x4 v; } pk;
        pk.w[0] = pack2bf(sc[cg][kbi][0], sc[cg][kbi][1]);
        pk.w[1] = pack2bf(sc[cg][kbi][2], sc[cg][kbi][3]);
        pkv[cg][kbi] = pk.v;
      }
    __builtin_amdgcn_s_setprio(1);
#pragma unroll
    for (int db = 0; db < 4; ++db) {
      int r = db * 16 + c;  // d row; r&15 == c
#pragma unroll
      for (int kbi = 0; kbi < 4; ++kbi) {
        int G = sub * 8 + kbi * 2 + (quad >> 1);  // 16B chunk in 128-key row
        bf16x4 vf = *(const bf16x4*)&Vs[cur][r * 128 + 8 * (G ^ (r & 15)) +
                                            (quad & 1) * 4];
        od[t][0][db] = mfma16k16(vf, pkv[0][kbi], od[t][0][db]);
        od[t][1][db] = mfma16k16(vf, pkv[1][kbi], od[t][1][db]);
      }
    }
    __builtin_amdgcn_s_setprio(0);
#else
    // fallback: shuffle P^T into K=32 B-frag layout, per col-group
#pragma unroll
    for (int cg = 0; cg < 2; ++cg) {
      u32 pk[4][2];
#pragma unroll
      for (int kbi = 0; kbi < 4; ++kbi) {
        pk[kbi][0] = pack2bf(sc[cg][kbi][0], sc[cg][kbi][1]);
        pk[kbi][1] = pack2bf(sc[cg][kbi][2], sc[cg][kbi][3]);
      }
      const int s0 = ((quad & 1) * 2) * 16 + c;
      const int s1 = s0 + 16;
      const bool hi = quad >= 2;
#pragma unroll
      for (int base = 0; base < 2; ++base) {
        u32 e0 = __shfl(pk[base * 2][0], s0);
        u32 e1 = __shfl(pk[base * 2][1], s0);
        u32 e2 = __shfl(pk[base * 2][0], s1);
        u32 e3 = __shfl(pk[base * 2][1], s1);
        u32 o0 = __shfl(pk[base * 2 + 1][0], s0);
        u32 o1 = __shfl(pk[base * 2 + 1][1], s0);
        u32 o2 = __shfl(pk[base * 2 + 1][0], s1);
        u32 o3 = __shfl(pk[base * 2 + 1][1], s1);
        union { u32 w[4]; bf16x8 v; } pf;
        pf.w[0] = hi ? o0 : e0;
        pf.w[1] = hi ? o1 : e1;
        pf.w[2] = hi ? o2 : e2;
        pf.w[3] = hi ? o3 : e3;
#pragma unroll
        for (int db = 0; db < 4; ++db) {
          int r = db * 16 + c;
          bf16x8 vf = *(const bf16x8*)&Vs[cur][r * 128 +
                          8 * ((sub * 8 + base * 4 + quad) ^ (r & 15))];
          od[t][cg][db] = mfma16(vf, pf.v, od[t][cg][db]);
        }
      }
    }
#endif
  };

  // prologue: stage super-tile 0, wait (syncthreads drains vmcnt)
  stage(0, 0);
  __syncthreads();
#pragma unroll 1
  for (int jj = 0; jj < NS; ++jj) {
    int cur = jj & 1;
    if (jj + 1 < NS) stage(cur ^ 1, jj + 1);  // prefetch next, no wait
#pragma unroll
    for (int sub = 0; sub < 2; ++sub) {
      int kt = 2 * jj + sub;
      if (kt <= qtl) apply(0, cur, sub, kt == qtl);
      if (kt <= qth) apply(1, cur, sub, kt == qth);
    }
    __syncthreads();  // vmcnt(0)+lgkmcnt(0)+barrier: next buffer ready
  }

#pragma unroll
  for (int t = 0; t < 2; ++t)
#pragma unroll
    for (int cg = 0; cg < 2; ++cg) {
      float inv = 1.0f / li[t][cg];
      int qrow = (t ? qth : qtl) * 64 + wq0 + cg * 16 + c;
      u16* op = ab + (size_t)(b * S_LEN + qrow) * DMODEL + h * DKH;
#pragma unroll
      for (int db = 0; db < 4; ++db) {
        u16x4 o4;
        o4.x = f2bf(od[t][cg][db][0] * inv);
        o4.y = f2bf(od[t][cg][db][1] * inv);
        o4.z = f2bf(od[t][cg][db][2] * inv);
        o4.w = f2bf(od[t][cg][db][3] * inv);
        *(u16x4*)&op[db * 16 + quad * 4] = o4;
      }
    }
}

extern "C" void kernel_launch(void* const* d_in, const int* in_sizes, int n_in,
                              void* d_out, int out_size, void* d_ws, size_t ws_size,
                              hipStream_t stream) {
  const float* x = (const float*)d_in[0];
  const int* pos = (const int*)d_in[1];
  const float* Wq = (const float*)d_in[2];
  const float* Wk = (const float*)d_in[3];
  const float* Wv = (const float*)d_in[4];
  const float* Wo = (const float*)d_in[5];
  float* out = (float*)d_out;

  char* w = (char*)d_ws;
  size_t o = 0;
  auto take = [&](size_t nbytes) {
    char* p = w + o;
    o += (nbytes + 255) & ~(size_t)255;
    return p;
  };
  const size_t actBytes = (size_t)BATCH * S_LEN * DMODEL * 2;
  const size_t wBytes = (size_t)DMODEL * DMODEL * 2;
  u16* xb   = (u16*)take(actBytes);
  u16* Wcat = (u16*)take(3 * wBytes);  // [3072][1024] = Wq;Wk;Wv
  u16* Wob  = (u16*)take(wBytes);
  u16* qb   = (u16*)take(actBytes);
  u16* kb   = (u16*)take(actBytes);
  u16* vt   = (u16*)take(actBytes);  // [B,H,DK,S]
  u16* ab   = (u16*)take(actBytes);
  float2* tab = (float2*)take((size_t)NTAB * sizeof(float2));

  // Fused casts + rope table: x + 4 weight matrices + 65536 tab entries.
  int ncast = NX4 + 4 * NW4 + NTAB;  // 3211264, exact multiple of 256
  cast_all<<<ncast / 256, 256, 0, stream>>>(x, Wq, Wk, Wv, Wo, xb, Wcat, Wob,
                                            pos, tab);

  // Fused QKV: [8192,1024] x [3072,1024]^T, RoPE fused in epilogue.
  gemm128<<<dim3(BATCH * S_LEN / 128, 3 * DMODEL / 128), 256, 0, stream>>>(
      xb, Wcat, qb, kb, vt, nullptr, tab, 0);

  attn3<<<dim3(8, BATCH * NHEAD), 256, 0, stream>>>(qb, kb, vt, ab);

  gemm128<<<dim3(BATCH * S_LEN / 128, DMODEL / 128), 256, 0, stream>>>(
      ab, Wob, nullptr, nullptr, nullptr, out, nullptr, 2);
}

// Round 10
// 242.538 us; speedup vs baseline: 1.1293x; 1.0448x over previous
//
#include <hip/hip_runtime.h>

// B=4, S=2048, D=1024, H=16, DK=64. RoPE (interleaved pairs) + causal MHA.
// R3..R8: no-max softmax S^T attention, 2-phase dbuf GEMM, RoPE fused into
// QKV epilogue (cos/sin table), attn 128-key super-tiles + XCD remap.
// R9/R10: counted-vmcnt gemm regressed (lost 2-blocks/CU overlap). Reverted.
// R12: cooperative-launch full fusion FAILED correctness (cross-XCD stale
//      reads through grid.sync) -> reverted to multi-launch.
// R13 (this round): R11 base + QKV gemm tile 128x128 -> 128x192:
//   LDS = 32KB(A) + 48KB(B) = exactly 80KB -> still 2 blocks/CU (the
//   mechanism that covers the 2-phase stalls). Per K-step MFMA 32->48
//   (+50% barrier amortization) at only +25% staging. Grid 64x16 = 1024
//   blocks = exactly 2 co-resident rounds. Out-proj stays 128x128.

typedef unsigned short u16;
typedef unsigned int u32;
typedef __attribute__((ext_vector_type(8))) short bf16x8;
typedef __attribute__((ext_vector_type(4))) short bf16x4;
typedef __attribute__((ext_vector_type(4))) float f32x4;
typedef __attribute__((ext_vector_type(4))) unsigned short u16x4;

#define S_LEN 2048
#define DMODEL 1024
#define NHEAD 16
#define DKH 64
#define BATCH 4
#define NT 32  // S_LEN/64 key tiles
#define NX4 (BATCH * S_LEN * DMODEL / 4)  // 2097152
#define NW4 (DMODEL * DMODEL / 4)         // 262144 = 2^18
#define NTAB (S_LEN * 32)                 // 65536 rope table entries

static __device__ __forceinline__ u16 f2bf(float f) {
  union { float f; u32 u; } v; v.f = f;
  u32 r = v.u + 0x7fffu + ((v.u >> 16) & 1u);  // RNE
  return (u16)(r >> 16);
}
#if __has_builtin(__builtin_amdgcn_cvt_pk_bf16_f32)
typedef __attribute__((ext_vector_type(2))) __bf16 bf2_t;
static __device__ __forceinline__ u32 pack2bf(float a, float b) {
  union { bf2_t h; u32 u; } cv;
  cv.h = __builtin_amdgcn_cvt_pk_bf16_f32(a, b);
  return cv.u;
}
#else
static __device__ __forceinline__ u32 pack2bf(float a, float b) {
  return (u32)f2bf(a) | ((u32)f2bf(b) << 16);
}
#endif
static __device__ __forceinline__ float fexp2(float x) {
#if __has_builtin(__builtin_amdgcn_exp2f)
  return __builtin_amdgcn_exp2f(x);
#else
  return exp2f(x);
#endif
}
static __device__ __forceinline__ f32x4 mfma16(bf16x8 a, bf16x8 b, f32x4 c) {
  return __builtin_amdgcn_mfma_f32_16x16x32_bf16(a, b, c, 0, 0, 0);
}
#if __has_builtin(__builtin_amdgcn_mfma_f32_16x16x16bf16_1k)
#define HAVE_MFMA_K16 1
static __device__ __forceinline__ f32x4 mfma16k16(bf16x4 a, bf16x4 b, f32x4 c) {
  return __builtin_amdgcn_mfma_f32_16x16x16bf16_1k(a, b, c, 0, 0, 0);
}
#else
#define HAVE_MFMA_K16 0
#endif
// Async global->LDS, 16B per lane. LDS dest = wave-uniform base + lane*16.
static __device__ __forceinline__ void glds16(const void* g, void* l) {
  __builtin_amdgcn_global_load_lds((const __attribute__((address_space(1))) u32*)g,
                                   (__attribute__((address_space(3))) u32*)l, 16, 0, 0);
}

// One fused pass: x + Wq,Wk,Wv -> Wcat + Wo -> Wob + RoPE cos/sin table.
__global__ __launch_bounds__(256) void cast_all(const float* __restrict__ x,
                                                const float* __restrict__ Wq,
                                                const float* __restrict__ Wk,
                                                const float* __restrict__ Wv,
                                                const float* __restrict__ Wo,
                                                u16* __restrict__ xb,
                                                u16* __restrict__ Wcat,
                                                u16* __restrict__ Wob,
                                                const int* __restrict__ pos,
                                                float2* __restrict__ tab) {
  int i = blockIdx.x * 256 + threadIdx.x;
  const float* s;
  u16* d;
  if (i < NX4) {
    s = x + (size_t)i * 4;
    d = xb + (size_t)i * 4;
  } else if (i < NX4 + 4 * NW4) {
    int j = i - NX4;
    int r = j >> 18;
    int off = j & (NW4 - 1);
    const float* W = r == 0 ? Wq : r == 1 ? Wk : r == 2 ? Wv : Wo;
    s = W + (size_t)off * 4;
    d = (r < 3 ? Wcat + (size_t)r * DMODEL * DMODEL : Wob) + (size_t)off * 4;
  } else {
    // rope table tail: tab[s*32+p] = {cos,sin}(pos[s] * 10000^(-2p/64))
    int j = i - (NX4 + 4 * NW4);  // [0, NTAB)
    int sq = j >> 5, p = j & 31;
    float ph = (float)pos[sq] * powf(10000.0f, -(float)(2 * p) / 64.0f);
    float sn, cs;
    sincosf(ph, &sn, &cs);
    tab[j] = make_float2(cs, sn);
    return;
  }
  u16x4 o;
  o.x = f2bf(s[0]); o.y = f2bf(s[1]); o.z = f2bf(s[2]); o.w = f2bf(s[3]);
  *(u16x4*)d = o;
}

// QKV GEMM with fused RoPE epilogue. C[m,n] = sum_k A[m,k]*W[n,k].
// 128x192 tile, 256 thr (4 waves, 2M x 2N of 64x96 each), BK=64, 2-phase
// double-buffered glds staging. LDS = 32KB(A)+48KB(B) = 80KB exactly ->
// 2 blocks/CU (the stall-cover mechanism). Epilogue: n<1024 q rot+scale,
// <2048 k rot, else v scatter to [B,H,DK,S].
__global__ __launch_bounds__(256, 2) void gemm192(const u16* __restrict__ A,
                                                  const u16* __restrict__ W,
                                                  u16* __restrict__ oq,
                                                  u16* __restrict__ ok,
                                                  u16* __restrict__ ov,
                                                  const float2* __restrict__ tab) {
  __shared__ __attribute__((aligned(16))) u16 As[2][128 * 64];  // 32 KB
  __shared__ __attribute__((aligned(16))) u16 Bs[2][192 * 64];  // 48 KB
  const int m0 = blockIdx.x * 128, n0 = blockIdx.y * 192;
  const int tid = threadIdx.x, lane = tid & 63, wave = tid >> 6;
  const int quad = lane >> 4, c = lane & 15;
  const int wm = (wave & 1) * 64, wn = (wave >> 1) * 96;
  const int ls = lane >> 3, lc = lane & 7;

  auto stage = [&](int buf, int ko) {
#pragma unroll
    for (int i = 0; i < 4; ++i) {           // A: 16 groups of 8 rows
      int rb = i * 32 + wave * 8;
      int r = rb + ls;
      glds16(&A[(size_t)(m0 + r) * DMODEL + ko + 8 * (lc ^ (r & 7))],
             &As[buf][rb * 64]);
    }
#pragma unroll
    for (int i = 0; i < 6; ++i) {           // B: 24 groups of 8 rows = 192
      int rb = i * 32 + wave * 8;
      int r = rb + ls;
      glds16(&W[(size_t)(n0 + r) * DMODEL + ko + 8 * (lc ^ (r & 7))],
             &Bs[buf][rb * 64]);
    }
  };

  f32x4 acc[4][6] = {};
  stage(0, 0);
  __syncthreads();
#pragma unroll 1
  for (int kt = 0; kt < DMODEL / 64; ++kt) {
    const int cur = kt & 1;
    if (kt < DMODEL / 64 - 1) stage(cur ^ 1, (kt + 1) * 64);  // prefetch, no wait
#pragma unroll
    for (int t = 0; t < 2; ++t) {
      bf16x8 af[4], bfr[6];
#pragma unroll
      for (int mb = 0; mb < 4; ++mb) {
        int r = wm + mb * 16 + c;
        af[mb] = *(const bf16x8*)&As[cur][r * 64 + 8 * ((t * 4 + quad) ^ (r & 7))];
      }
#pragma unroll
      for (int nb = 0; nb < 6; ++nb) {
        int r = wn + nb * 16 + c;
        bfr[nb] = *(const bf16x8*)&Bs[cur][r * 64 + 8 * ((t * 4 + quad) ^ (r & 7))];
      }
#pragma unroll
      for (int mb = 0; mb < 4; ++mb)
#pragma unroll
        for (int nb = 0; nb < 6; ++nb)
          acc[mb][nb] = mfma16(af[mb], bfr[nb], acc[mb][nb]);
    }
    __syncthreads();  // vmcnt(0)+barrier: prefetched buffer ready for kt+1
  }
#pragma unroll
  for (int mb = 0; mb < 4; ++mb) {
    int mrow = m0 + wm + mb * 16 + quad * 4;
#pragma unroll
    for (int nb = 0; nb < 6; ++nb) {
      int n = n0 + wn + nb * 16 + c;
      f32x4 v = acc[mb][nb];
      if (n < 2 * DMODEL) {
        // fused RoPE: pair partner (d^1) is in neighbor lane (c parity == n
        // parity: n0/wn/nb*16 all even). Wave-uniform branch region
        // (fragment n-base 16-aligned, no q/k straddle within a fragment).
        const bool isq = n < DMODEL;
        const int p = (n & 63) >> 1;  // pair index within head
        const bool odd = n & 1;
        u16* dst = isq ? oq : ok;
        const int ncol = n & (DMODEL - 1);
#pragma unroll
        for (int r = 0; r < 4; ++r) {
          float v1 = v[r];
          float v2 = __shfl_xor(v1, 1);
          float x1 = odd ? v2 : v1;
          float x2 = odd ? v1 : v2;
          int s = (mrow + r) & (S_LEN - 1);
          float2 t2 = tab[s * 32 + p];
          float rv = odd ? (x1 * t2.y + x2 * t2.x) : (x1 * t2.x - x2 * t2.y);
          if (isq) rv *= 0.18033688011112042f;  // 0.125 * log2(e)
          dst[(size_t)(mrow + r) * DMODEL + ncol] = f2bf(rv);
        }
      } else {
        int nn = n - 2 * DMODEL;
        int h = nn >> 6, d = nn & 63;
        int b = mrow >> 11, s = mrow & (S_LEN - 1);
        u16x4 p4;
        p4.x = f2bf(v[0]); p4.y = f2bf(v[1]); p4.z = f2bf(v[2]); p4.w = f2bf(v[3]);
        *(u16x4*)&ov[((size_t)(b * NHEAD + h) * DKH + d) * S_LEN + s] = p4;
      }
    }
  }
}

// Out-projection GEMM (R7-proven 128x128 2-phase), fp32 store.
__global__ __launch_bounds__(256) void gemm128(const u16* __restrict__ A,
                                               const u16* __restrict__ W,
                                               float* __restrict__ of) {
  __shared__ __attribute__((aligned(16))) u16 As[2][128 * 64];
  __shared__ __attribute__((aligned(16))) u16 Bs[2][128 * 64];
  const int m0 = blockIdx.x * 128, n0 = blockIdx.y * 128;
  const int tid = threadIdx.x, lane = tid & 63, wave = tid >> 6;
  const int quad = lane >> 4, c = lane & 15;
  const int wm = (wave & 1) * 64, wn = (wave >> 1) * 64;
  const int ls = lane >> 3, lc = lane & 7;

  auto stage = [&](int buf, int ko) {
#pragma unroll
    for (int i = 0; i < 4; ++i) {
      int rb = i * 32 + wave * 8;
      int r = rb + ls;
      int kA = ko + 8 * (lc ^ (r & 7));
      glds16(&A[(size_t)(m0 + r) * DMODEL + kA], &As[buf][rb * 64]);
      glds16(&W[(size_t)(n0 + r) * DMODEL + kA], &Bs[buf][rb * 64]);
    }
  };

  f32x4 acc[4][4] = {};
  stage(0, 0);
  __syncthreads();
#pragma unroll 1
  for (int kt = 0; kt < DMODEL / 64; ++kt) {
    const int cur = kt & 1;
    if (kt < DMODEL / 64 - 1) stage(cur ^ 1, (kt + 1) * 64);  // prefetch, no wait
#pragma unroll
    for (int t = 0; t < 2; ++t) {
      bf16x8 af[4], bfr[4];
#pragma unroll
      for (int mb = 0; mb < 4; ++mb) {
        int r = wm + mb * 16 + c;
        af[mb] = *(const bf16x8*)&As[cur][r * 64 + 8 * ((t * 4 + quad) ^ (r & 7))];
      }
#pragma unroll
      for (int nb = 0; nb < 4; ++nb) {
        int r = wn + nb * 16 + c;
        bfr[nb] = *(const bf16x8*)&Bs[cur][r * 64 + 8 * ((t * 4 + quad) ^ (r & 7))];
      }
#pragma unroll
      for (int mb = 0; mb < 4; ++mb)
#pragma unroll
        for (int nb = 0; nb < 4; ++nb)
          acc[mb][nb] = mfma16(af[mb], bfr[nb], acc[mb][nb]);
    }
    __syncthreads();  // vmcnt(0)+barrier: prefetched buffer ready for kt+1
  }
#pragma unroll
  for (int mb = 0; mb < 4; ++mb) {
    int mrow = m0 + wm + mb * 16 + quad * 4;
#pragma unroll
    for (int nb = 0; nb < 4; ++nb) {
      int n = n0 + wn + nb * 16 + c;
      f32x4 v = acc[mb][nb];
#pragma unroll
      for (int r = 0; r < 4; ++r) of[(size_t)(mrow + r) * DMODEL + n] = v[r];
    }
  }
}

// Flash attention, S^T formulation, no-max softmax. (R11 body.)
// Grid (8, B*H), 256 threads (4 waves). Block owns TWO merged q-tile pairs:
//   waves 0-1: pair A = (2x, 31-2x); waves 2-3: pair B = (2x+1, 30-2x).
// Each wave owns 32 q-cols (two 16-col groups). K/V staged in 128-key
// SUPER-TILES (Ks[2][128x64], Vs[2][64x128], 64KB, 2 blocks/CU): one
// stage+barrier round feeds two 64-key sub-tile applies per pair.
// V rows are 256B: 16-chunk XOR swizzle ^(r&15). XCD remap keeps each
// (b,h)'s 8 blocks on one XCD. setprio around MFMA.
__global__ __launch_bounds__(256, 2) void attn3(const u16* __restrict__ qb,
                                                const u16* __restrict__ kb,
                                                const u16* __restrict__ vt,
                                                u16* __restrict__ ab) {
  __shared__ __attribute__((aligned(16))) u16 Ks[2][128 * 64];  // [key][d] swz
  __shared__ __attribute__((aligned(16))) u16 Vs[2][64 * 128];  // [d][key] swz
  const int L = blockIdx.x + 8 * blockIdx.y;
  const int xcd = L & 7, slot = L >> 3;   // slot in [0,64)
  const int bhl = slot >> 3;              // local head in [0,8)
  const int xs = slot & 7;
  const int x = (bhl & 4) ? 7 - xs : xs;  // complementary-x tail balance
  const int bh = xcd * 8 + bhl;
  const int b = bh >> 4, h = bh & 15;
  const int tid = threadIdx.x, lane = tid & 63, wave = tid >> 6;
  const int g = wave >> 1;   // 0: pair A, 1: pair B
  const int wh = wave & 1;   // 32-col half within tile
  const int quad = lane >> 4, c = lane & 15;
  const int ls = lane >> 3, lc = lane & 7;    // K staging: 8 rows x 8 chunks
  const int ls2 = lane >> 4, lc2 = lane & 15; // V staging: 4 rows x 16 chunks
  const int wq0 = wh * 32;   // base q-col of this wave's 32 cols
  const int qtl = 2 * x + g, qth = 31 - 2 * x - g;
  const int J = 31 - 2 * x;      // max key tile (odd)
  const int NS = (J + 1) >> 1;   // 128-key super-tiles
  const float NEG = -3.0e38f;

  // qf[t][cg][dh]: q fragment for tile t, 16-col group cg, d-half dh
  bf16x8 qf[2][2][2];
#pragma unroll
  for (int t = 0; t < 2; ++t)
#pragma unroll
    for (int cg = 0; cg < 2; ++cg) {
      int qrow = (t ? qth : qtl) * 64 + wq0 + cg * 16 + c;
      const u16* qp = qb + (size_t)(b * S_LEN + qrow) * DMODEL + h * DKH;
      qf[t][cg][0] = *(const bf16x8*)&qp[quad * 8];
      qf[t][cg][1] = *(const bf16x8*)&qp[32 + quad * 8];
    }
  float li[2][2] = {};
  f32x4 od[2][2][4] = {};

  // stage 128-key super-tile jj into buffer buf (8 glds/wave, no wait)
  auto stage = [&](int buf, int jj) {
    // K: 128 rows (keys) x 64 d; wave stages 32 rows as 4 glds of 8 rows
#pragma unroll
    for (int i = 0; i < 4; ++i) {
      int rb = wave * 32 + i * 8;
      int r = rb + ls;
      glds16(&kb[(size_t)(b * S_LEN + jj * 128 + r) * DMODEL + h * DKH +
                 8 * (lc ^ (r & 7))],
             &Ks[buf][rb * 64]);
    }
    // V: 64 rows (d) x 128 keys; wave stages 16 rows as 4 glds of 4 rows
#pragma unroll
    for (int i = 0; i < 4; ++i) {
      int rb = wave * 16 + i * 4;
      int r = rb + ls2;
      glds16(&vt[((size_t)bh * DKH + r) * S_LEN + jj * 128 +
                 8 * (lc2 ^ (r & 15))],
             &Vs[buf][rb * 128]);
    }
  };

  // one q-tile application against 64-key sub-tile sub of buffer cur
  auto apply = [&](int t, int cur, int sub, bool diag) {
    f32x4 sc[2][4];
    __builtin_amdgcn_s_setprio(1);
#pragma unroll
    for (int kbi = 0; kbi < 4; ++kbi) {
      int r = sub * 64 + kbi * 16 + c;  // r&7 == c&7
      bf16x8 k0 = *(const bf16x8*)&Ks[cur][r * 64 + 8 * (quad ^ (r & 7))];
      bf16x8 k1 = *(const bf16x8*)&Ks[cur][r * 64 + 8 * ((4 + quad) ^ (r & 7))];
#pragma unroll
      for (int cg = 0; cg < 2; ++cg) {
        f32x4 a = {};
        a = mfma16(k0, qf[t][cg][0], a);
        a = mfma16(k1, qf[t][cg][1], a);
        sc[cg][kbi] = a;  // already log2-domain (q pre-scaled)
      }
    }
    __builtin_amdgcn_s_setprio(0);
    if (diag) {
#pragma unroll
      for (int cg = 0; cg < 2; ++cg)
#pragma unroll
        for (int kbi = 0; kbi < 4; ++kbi)
#pragma unroll
          for (int r = 0; r < 4; ++r)
            if (kbi * 16 + quad * 4 + r > wq0 + cg * 16 + c) sc[cg][kbi][r] = NEG;
    }
    float rs[2] = {0.f, 0.f};
#pragma unroll
    for (int cg = 0; cg < 2; ++cg)
#pragma unroll
      for (int kbi = 0; kbi < 4; ++kbi)
#pragma unroll
        for (int r = 0; r < 4; ++r) {
          float p = fexp2(sc[cg][kbi][r]);
          sc[cg][kbi][r] = p;
          rs[cg] += p;
        }
#pragma unroll
    for (int cg = 0; cg < 2; ++cg) {
      float v = rs[cg];
      v += __shfl_xor(v, 16);
      v += __shfl_xor(v, 32);
      li[t][cg] += v;
    }
#if HAVE_MFMA_K16
    // pkv[cg][kbi] = keys kbi*16+quad*4+{0..3} for q-col c == 16x16x16 B-frag
    bf16x4 pkv[2][4];
#pragma unroll
    for (int cg = 0; cg < 2; ++cg)
#pragma unroll
      for (int kbi = 0; kbi < 4; ++kbi) {
        union { u32 w[2]; bf16x4 v; } pk;
        pk.w[0] = pack2bf(sc[cg][kbi][0], sc[cg][kbi][1]);
        pk.w[1] = pack2bf(sc[cg][kbi][2], sc[cg][kbi][3]);
        pkv[cg][kbi] = pk.v;
      }
    __builtin_amdgcn_s_setprio(1);
#pragma unroll
    for (int db = 0; db < 4; ++db) {
      int r = db * 16 + c;  // d row; r&15 == c
#pragma unroll
      for (int kbi = 0; kbi < 4; ++kbi) {
        int G = sub * 8 + kbi * 2 + (quad >> 1);  // 16B chunk in 128-key row
        bf16x4 vf = *(const bf16x4*)&Vs[cur][r * 128 + 8 * (G ^ (r & 15)) +
                                            (quad & 1) * 4];
        od[t][0][db] = mfma16k16(vf, pkv[0][kbi], od[t][0][db]);
        od[t][1][db] = mfma16k16(vf, pkv[1][kbi], od[t][1][db]);
      }
    }
    __builtin_amdgcn_s_setprio(0);
#else
    // fallback: shuffle P^T into K=32 B-frag layout, per col-group
#pragma unroll
    for (int cg = 0; cg < 2; ++cg) {
      u32 pk[4][2];
#pragma unroll
      for (int kbi = 0; kbi < 4; ++kbi) {
        pk[kbi][0] = pack2bf(sc[cg][kbi][0], sc[cg][kbi][1]);
        pk[kbi][1] = pack2bf(sc[cg][kbi][2], sc[cg][kbi][3]);
      }
      const int s0 = ((quad & 1) * 2) * 16 + c;
      const int s1 = s0 + 16;
      const bool hi = quad >= 2;
#pragma unroll
      for (int base = 0; base < 2; ++base) {
        u32 e0 = __shfl(pk[base * 2][0], s0);
        u32 e1 = __shfl(pk[base * 2][1], s0);
        u32 e2 = __shfl(pk[base * 2][0], s1);
        u32 e3 = __shfl(pk[base * 2][1], s1);
        u32 o0 = __shfl(pk[base * 2 + 1][0], s0);
        u32 o1 = __shfl(pk[base * 2 + 1][1], s0);
        u32 o2 = __shfl(pk[base * 2 + 1][0], s1);
        u32 o3 = __shfl(pk[base * 2 + 1][1], s1);
        union { u32 w[4]; bf16x8 v; } pf;
        pf.w[0] = hi ? o0 : e0;
        pf.w[1] = hi ? o1 : e1;
        pf.w[2] = hi ? o2 : e2;
        pf.w[3] = hi ? o3 : e3;
#pragma unroll
        for (int db = 0; db < 4; ++db) {
          int r = db * 16 + c;
          bf16x8 vf = *(const bf16x8*)&Vs[cur][r * 128 +
                          8 * ((sub * 8 + base * 4 + quad) ^ (r & 15))];
          od[t][cg][db] = mfma16(vf, pf.v, od[t][cg][db]);
        }
      }
    }
#endif
  };

  // prologue: stage super-tile 0, wait (syncthreads drains vmcnt)
  stage(0, 0);
  __syncthreads();
#pragma unroll 1
  for (int jj = 0; jj < NS; ++jj) {
    int cur = jj & 1;
    if (jj + 1 < NS) stage(cur ^ 1, jj + 1);  // prefetch next, no wait
#pragma unroll
    for (int sub = 0; sub < 2; ++sub) {
      int kt = 2 * jj + sub;
      if (kt <= qtl) apply(0, cur, sub, kt == qtl);
      if (kt <= qth) apply(1, cur, sub, kt == qth);
    }
    __syncthreads();  // vmcnt(0)+lgkmcnt(0)+barrier: next buffer ready
  }

#pragma unroll
  for (int t = 0; t < 2; ++t)
#pragma unroll
    for (int cg = 0; cg < 2; ++cg) {
      float inv = 1.0f / li[t][cg];
      int qrow = (t ? qth : qtl) * 64 + wq0 + cg * 16 + c;
      u16* op = ab + (size_t)(b * S_LEN + qrow) * DMODEL + h * DKH;
#pragma unroll
      for (int db = 0; db < 4; ++db) {
        u16x4 o4;
        o4.x = f2bf(od[t][cg][db][0] * inv);
        o4.y = f2bf(od[t][cg][db][1] * inv);
        o4.z = f2bf(od[t][cg][db][2] * inv);
        o4.w = f2bf(od[t][cg][db][3] * inv);
        *(u16x4*)&op[db * 16 + quad * 4] = o4;
      }
    }
}

extern "C" void kernel_launch(void* const* d_in, const int* in_sizes, int n_in,
                              void* d_out, int out_size, void* d_ws, size_t ws_size,
                              hipStream_t stream) {
  const float* x = (const float*)d_in[0];
  const int* pos = (const int*)d_in[1];
  const float* Wq = (const float*)d_in[2];
  const float* Wk = (const float*)d_in[3];
  const float* Wv = (const float*)d_in[4];
  const float* Wo = (const float*)d_in[5];
  float* out = (float*)d_out;

  char* w = (char*)d_ws;
  size_t o = 0;
  auto take = [&](size_t nbytes) {
    char* p = w + o;
    o += (nbytes + 255) & ~(size_t)255;
    return p;
  };
  const size_t actBytes = (size_t)BATCH * S_LEN * DMODEL * 2;
  const size_t wBytes = (size_t)DMODEL * DMODEL * 2;
  u16* xb   = (u16*)take(actBytes);
  u16* Wcat = (u16*)take(3 * wBytes);  // [3072][1024] = Wq;Wk;Wv
  u16* Wob  = (u16*)take(wBytes);
  u16* qb   = (u16*)take(actBytes);
  u16* kb   = (u16*)take(actBytes);
  u16* vt   = (u16*)take(actBytes);  // [B,H,DK,S]
  u16* ab   = (u16*)take(actBytes);
  float2* tab = (float2*)take((size_t)NTAB * sizeof(float2));

  // Fused casts + rope table: x + 4 weight matrices + 65536 tab entries.
  int ncast = NX4 + 4 * NW4 + NTAB;  // 3211264, exact multiple of 256
  cast_all<<<ncast / 256, 256, 0, stream>>>(x, Wq, Wk, Wv, Wo, xb, Wcat, Wob,
                                            pos, tab);

  // Fused QKV: [8192,1024] x [3072,1024]^T, RoPE fused in epilogue.
  // 128x192 tiles: grid (64, 16) = 1024 blocks = 2 exact CU rounds.
  gemm192<<<dim3(BATCH * S_LEN / 128, 3 * DMODEL / 192), 256, 0, stream>>>(
      xb, Wcat, qb, kb, vt, tab);

  attn3<<<dim3(8, BATCH * NHEAD), 256, 0, stream>>>(qb, kb, vt, ab);

  gemm128<<<dim3(BATCH * S_LEN / 128, DMODEL / 128), 256, 0, stream>>>(
      ab, Wob, out);
}